// Round 4
// baseline (355.943 us; speedup 1.0000x reference)
//
#include <hip/hip_runtime.h>
#include <math.h>

typedef unsigned short u16;
typedef unsigned int   u32;
using f32x4  = __attribute__((ext_vector_type(4))) float;
using bf16x8 = __attribute__((ext_vector_type(8))) __bf16;

#define HIDDEN   2880
#define QKVD     5120
#define QD       4096
#define TTOK     2048
#define NKV      8
#define QMULT    8
#define HD       64
#define NPAD     2944   // w_out rows padded to 23*128 (GEMM2 store-guards col<2944)

// prep grid partition (w_out cvt rides in GEMM1's idle CUs / tail)
#define PREP_QKV_BLOCKS  14400   // QKVD*HIDDEN/4/256
#define PREP_RMS_BLOCKS  2048

static __device__ __forceinline__ float bflo(u32 u){ return __uint_as_float(u << 16); }
static __device__ __forceinline__ float bfhi(u32 u){ return __uint_as_float(u & 0xffff0000u); }
static __device__ __forceinline__ u16 f2bf(float f){
    u32 u = __float_as_uint(f);
    u32 r = (u + 0x7fffu + ((u >> 16) & 1u)) >> 16;
    return (u16)r;
}

static __device__ __forceinline__ void glds16(const void* g, void* l) {
    __builtin_amdgcn_global_load_lds(
        (__attribute__((address_space(1))) void*)g,
        (__attribute__((address_space(3))) void*)l,
        16, 0, 0);
}

// raw barrier: no implicit vmcnt(0) drain (keeps global_load_lds in flight across it)
#define BAR() asm volatile("s_barrier" ::: "memory")

// ---------------- fused prep: w_qkv cvt | rmsnorm ----------------
__global__ __launch_bounds__(256) void prep_kernel(const float* __restrict__ w_qkv,
                                                   u16* __restrict__ wqkv_bf,
                                                   const float* __restrict__ x,
                                                   const float* __restrict__ scale,
                                                   u16* __restrict__ h) {
    const int b = blockIdx.x;
    const int tid = threadIdx.x;
    if (b < PREP_QKV_BLOCKS) {
        int i = b * 256 + tid;
        float4 f = ((const float4*)w_qkv)[i];
        ushort4 o;
        o.x = f2bf(f.x); o.y = f2bf(f.y); o.z = f2bf(f.z); o.w = f2bf(f.w);
        ((ushort4*)wqkv_bf)[i] = o;
    } else {
        const int t = b - PREP_QKV_BLOCKS;
        const float4* xr = (const float4*)(x + (long)t * HIDDEN);
        float4 v[3];
        float ss = 0.f;
        #pragma unroll
        for (int it = 0; it < 3; ++it) {
            int i4 = tid + it * 256;
            if (i4 < 720) {
                v[it] = xr[i4];
                ss += v[it].x*v[it].x + v[it].y*v[it].y + v[it].z*v[it].z + v[it].w*v[it].w;
            }
        }
        #pragma unroll
        for (int off = 32; off > 0; off >>= 1) ss += __shfl_down(ss, off);
        __shared__ float red[4];
        if ((tid & 63) == 0) red[tid >> 6] = ss;
        __syncthreads();
        float tot = red[0] + red[1] + red[2] + red[3];
        float rr = rsqrtf(tot * (1.0f / HIDDEN) + 1e-5f);
        ushort4* hr = (ushort4*)(h + (long)t * HIDDEN);
        #pragma unroll
        for (int it = 0; it < 3; ++it) {
            int i4 = tid + it * 256;
            if (i4 < 720) {
                float4 s4 = ((const float4*)scale)[i4];
                ushort4 o;
                o.x = f2bf(v[it].x * rr * s4.x);
                o.y = f2bf(v[it].y * rr * s4.y);
                o.z = f2bf(v[it].z * rr * s4.z);
                o.w = f2bf(v[it].w * rr * s4.w);
                hr[i4] = o;
            }
        }
    }
}

// ---- 4-barrier-per-K-tile 256x256/BK=64 GEMM: C = A[M,K] @ B[N,K]^T (bf16) ------
// R4 change vs R3: R2/R3 measured per-tile time = matrix work (2483cy) + LDS work
// (2304cy) ADDITIVE -- the load|barrier|MFMA|barrier lockstep never overlaps the
// two pipes. The load->MFMA barrier has no correctness role (regs only), so each
// window is now {ds_read next-quad ; stage ; MFMA current-quad ; BAR}: reads
// process on the LDS pipe while the same window's (independent) MFMAs run on the
// matrix pipe. 4 barriers/tile instead of 8.
// Windows (tile t), all reads feed the NEXT window's MFMA:
//   W1: read B(t).q1->O ; stage Bh1(t+1), A(t+2) ; MFMA q0 (E,aq) ; BAR
//   W2: read B(t).q2->E ;                          MFMA q1 (O)    ; BAR
//   W3: read B(t).q3->O ;           vmcnt(4)     ; MFMA q2 (E)    ; BAR
//   W4: read B(t+1).q0->E ; stage Bh0(t+2) ; MFMA q3 (O) ; read aq<-A(t+1) ; BAR
// vmcnt(4)@W3-end: per-wave outstanding = Bh0(t+1)[W4(t-1)](2), Bh1(t+1)[W1](2),
// A(t+2)[W1](4) = 8 -> leaves newest 4 (A(t+2)); everything older (A(t+1), both
// B(t+1) halves) confirmed; the following barrier propagates across waves before
// W4 reads slot t+1. Tail (no A(t+2) staged): vmcnt(0). Never 0 mid-loop.
// Slot safety: every stage is issued >=1 barrier after the previous occupant's
// last ds_read (A slot t&1: read W4(t-1), written from W1(t); B slot (t+1)&1:
// read W3(t-1), written from W4(t-1)/W1(t); Bh0(t+2)->slot t&1: read W3(t),
// written from W4(t) after W3's barrier).
// NT is computed from K-kbase so uneven split-K (z=2 fallback: 23/22 tiles) works.

#define READ_BQ(SET, BASE, NQ) do { \
    SET[0][0] = *(const bf16x8*)((BASE) + (2*(NQ)+0)*2048 + off0); \
    SET[0][1] = *(const bf16x8*)((BASE) + (2*(NQ)+0)*2048 + off1); \
    SET[1][0] = *(const bf16x8*)((BASE) + (2*(NQ)+1)*2048 + off0); \
    SET[1][1] = *(const bf16x8*)((BASE) + (2*(NQ)+1)*2048 + off1); \
} while (0)

#define READ_AQ(BASE) do { \
    _Pragma("unroll") \
    for (int mi_ = 0; mi_ < 4; ++mi_) { \
        aq[mi_][0] = *(const bf16x8*)((BASE) + mi_*2048 + off0); \
        aq[mi_][1] = *(const bf16x8*)((BASE) + mi_*2048 + off1); \
    } \
} while (0)

#define MFMA_N(NQ, SET) do { \
    __builtin_amdgcn_s_setprio(1); \
    _Pragma("unroll") \
    for (int mi_ = 0; mi_ < 4; ++mi_) { \
        _Pragma("unroll") \
        for (int j_ = 0; j_ < 2; ++j_) { \
            acc[mi_][2*(NQ)+j_] = __builtin_amdgcn_mfma_f32_16x16x32_bf16(aq[mi_][0], SET[j_][0], acc[mi_][2*(NQ)+j_], 0, 0, 0); \
            acc[mi_][2*(NQ)+j_] = __builtin_amdgcn_mfma_f32_16x16x32_bf16(aq[mi_][1], SET[j_][1], acc[mi_][2*(NQ)+j_], 0, 0, 0); \
        } \
    } \
    __builtin_amdgcn_s_setprio(0); \
} while (0)

__global__ __launch_bounds__(512, 2) void gemm_bt_8ph(const u16* __restrict__ A,
                                                      const u16* __restrict__ B,
                                                      u16* __restrict__ C0,
                                                      int N, int K, int ksplit,
                                                      int blimit, int colmax,
                                                      int nz_gemm,
                                                      const float* __restrict__ wout_src,
                                                      u16* __restrict__ wout_dst) {
    const int tid  = threadIdx.x;

    if ((int)blockIdx.z >= nz_gemm) {
        // ---- filler blocks: w_out cvt+pad [HIDDEN][QD] f32 -> [NPAD][QD] bf16 ----
        const long nb = (long)gridDim.x * gridDim.y;
        long bidx = (long)blockIdx.y * gridDim.x + blockIdx.x;
        long i = bidx * 512 + tid;
        const long tot = (long)NPAD * QD / 4;
        const long stride = nb * 512;
        for (; i < tot; i += stride) {
            long idx = i * 4;
            int row = (int)(idx >> 12);
            int col = (int)(idx & 4095);
            ushort4 o;
            if (row < HIDDEN) {
                float4 f = *(const float4*)(wout_src + (long)row * QD + col);
                o.x = f2bf(f.x); o.y = f2bf(f.y); o.z = f2bf(f.z); o.w = f2bf(f.w);
            } else {
                o.x = 0; o.y = 0; o.z = 0; o.w = 0;
            }
            ((ushort4*)wout_dst)[i] = o;
        }
        return;
    }

    extern __shared__ u16 smem[];
    u16* const smA = smem;                  // [2][256][64] bf16 (32 KB/slot)
    u16* const smB = smem + 2 * 256 * 64;   // byte 65536, [2][256][64]
    const int lane = tid & 63;
    const int wv   = tid >> 6;              // wave 0..7
    const int wm2  = wv >> 1;               // 0..3 (M quad, 64 rows)
    const int wn2  = wv & 1;                // 0..1 (N half, 128 cols)
    const long m0  = (long)blockIdx.y * 256;
    const long n0  = (long)blockIdx.x * 256;
    const int kbase = blockIdx.z * ksplit;
    int krem = K - kbase; if (krem > ksplit) krem = ksplit;
    const int NT   = krem >> 6;             // K-tiles of 64 (handles uneven split)
    u16* C = C0 + (size_t)blockIdx.z * ((size_t)TTOK * N);

    // staging: per-thread 16B granule; source column pre-swizzled (rule #21 pair)
    const int srow = tid >> 3;                              // 0..63
    const int sg8  = ((tid & 7) ^ (srow & 7)) << 3;         // src elem offset
    // fragment reads: swizzle folds to per-lane constants (row&7 == lane&7)
    const int fr   = lane & 15;
    const int off0 = ((lane >> 4) << 4) ^ ((lane & 7) << 4);
    const int off1 = off0 ^ 64;
    const char* aR = (const char*)smA + (wm2 * 64  + fr) * 128;
    const char* bR = (const char*)smB + (wn2 * 128 + fr) * 128;

    f32x4 acc[4][8];
    #pragma unroll
    for (int i = 0; i < 4; ++i)
        #pragma unroll
        for (int j = 0; j < 8; ++j) acc[i][j] = f32x4{0.f, 0.f, 0.f, 0.f};

    const u16* Asrc = A + (m0 + srow) * (long)K + kbase + sg8;
    auto stageA = [&](int t) {
        char* dst = (char*)smA + (t & 1) * 32768 + wv * 1024;
        const u16* src = Asrc + t * 64;
        #pragma unroll
        for (int hj = 0; hj < 4; ++hj)
            glds16(src + (size_t)(hj * 64) * K, dst + hj * 8192);
    };
    auto stageBh = [&](int t, int h) {
        char* dst = (char*)smB + (t & 1) * 32768 + (h * 128 + wv * 8) * 128;
        #pragma unroll
        for (int j = 0; j < 2; ++j) {
            long r = n0 + h * 128 + j * 64 + srow;
            if (r > blimit) r = blimit;   // clamp into zero-padded rows
            glds16(B + (size_t)r * K + kbase + t * 64 + sg8, dst + j * 8192);
        }
    };

    bf16x8 aq[4][2], bqE[2][2], bqO[2][2];

    // prologue: stage A(0),B(0) and A(1),Bh0(1) (Bh1(1) comes in W1(0), matching
    // steady state where W4(t-1) stages Bh0(t+1)). 14 loads issued; vmcnt(6)
    // leaves newest 6 (A(1)+Bh0(1)) => A(0),B(0) landed.
    stageA(0);
    stageBh(0, 0); stageBh(0, 1);
    if (NT > 1) {
        stageA(1);
        stageBh(1, 0);
        asm volatile("s_waitcnt vmcnt(6)" ::: "memory");
    } else {
        asm volatile("s_waitcnt vmcnt(0)" ::: "memory");
    }
    BAR();
    READ_BQ(bqE, bR, 0);      // B(0).q0
    READ_AQ(aR);              // A(0)
    BAR();

    for (int t = 0; t < NT; ++t) {
        const char* aS1 = aR + ((t + 1) & 1) * 32768;   // A slot t+1
        const char* bS  = bR + (t & 1) * 32768;         // B slot t
        const char* bS1 = bR + ((t + 1) & 1) * 32768;   // B slot t+1
        // ---- W1: read q1; stage Bh1(t+1) THEN A(t+2) (issue order = vmcnt proof);
        //      MFMA q0 overlaps the reads on the other pipe
        READ_BQ(bqO, bS, 1);
        if (t + 1 < NT) stageBh(t + 1, 1);
        if (t + 2 < NT) stageA(t + 2);
        MFMA_N(0, bqE);
        BAR();
        // ---- W2: read q2; MFMA q1
        READ_BQ(bqE, bS, 2);
        MFMA_N(1, bqO);
        BAR();
        // ---- W3: read q3; MFMA q2; counted checkpoint BEFORE the barrier
        READ_BQ(bqO, bS, 3);
        MFMA_N(2, bqE);
        if (t + 2 < NT)      asm volatile("s_waitcnt vmcnt(4)" ::: "memory");
        else if (t + 1 < NT) asm volatile("s_waitcnt vmcnt(0)" ::: "memory");
        BAR();
        // ---- W4: read next tile's q0 + aq (slot t+1 confirmed above); stage
        //      Bh0(t+2) into slot t&1 (B(t) reads ended at W3's barrier); MFMA q3
        if (t + 1 < NT) READ_BQ(bqE, bS1, 0);
        if (t + 2 < NT) stageBh(t + 2, 0);
        MFMA_N(3, bqO);
        if (t + 1 < NT) READ_AQ(aS1);
        BAR();
    }

    // epilogue: C/D layout col=lane&15, row=(lane>>4)*4+reg  [m89-verified]
    const int cr = (lane >> 4) * 4;
    const int cc = lane & 15;
    #pragma unroll
    for (int nf = 0; nf < 8; ++nf) {
        long col = n0 + wn2 * 128 + nf * 16 + cc;
        if (col < colmax) {
            #pragma unroll
            for (int mi = 0; mi < 4; ++mi) {
                long row = m0 + wm2 * 64 + mi * 16 + cr;
                #pragma unroll
                for (int r2 = 0; r2 < 4; ++r2)
                    C[(row + r2) * (long)N + col] = f2bf(acc[mi][nf][r2]);
            }
        }
    }
}

// ------- RoPE (YaRN), consumes nsplit GEMM1 split-K partials + bias -------------
__global__ __launch_bounds__(256) void rope_kernel(const u16* __restrict__ p1,
                                                   const float* __restrict__ b_qkv,
                                                   u16* __restrict__ qr,
                                                   u16* __restrict__ kr,
                                                   u16* __restrict__ vr,
                                                   int nsplit) {
    const int t = blockIdx.x;
    const int tid = threadIdx.x;
    __shared__ float cs[32], sn[32];
    if (tid < 32) {
        float fi = (float)tid;
        float freq   = exp2f(17.1946032f * (fi * (1.0f / 32.0f)));   // 150000^(i/32)
        float interp = 1.0f / (32.0f * freq);
        float extra  = 1.0f / freq;
        float ramp   = (fi - 8.0927802f) * (1.0f / (17.3980220f - 8.0927802f));
        float rc     = fminf(fmaxf(ramp, 0.0f), 1.0f);               // = 1 - mask
        float invf   = interp * rc + extra * (1.0f - rc);
        float ang    = (float)t * invf;
        cs[tid] = cosf(ang) * 1.3465736f;                            // * concentration
        sn[tid] = sinf(ang) * 1.3465736f;
    }
    __syncthreads();
    const u16* rowA = p1 + (long)t * QKVD;
    auto pair = [&](int col) -> float2 {
        float2 bb = *(const float2*)(b_qkv + col);
        float a = bb.x, b = bb.y;
        for (int s = 0; s < nsplit; ++s) {
            u32 u = *(const u32*)(rowA + (size_t)s * TTOK * QKVD + col);
            a += bflo(u); b += bfhi(u);
        }
        return make_float2(a, b);
    };
    // Q: 64 heads x 32 pairs
    for (int p = tid; p < 2048; p += 256) {
        int hd2 = p >> 5, i = p & 31;
        float2 ab = pair(hd2 * 64 + 2 * i);
        float o1 = ab.x * cs[i] - ab.y * sn[i];
        float o2 = ab.y * cs[i] + ab.x * sn[i];
        *(u32*)(qr + (long)t * QD + hd2 * 64 + 2 * i) = (u32)f2bf(o1) | ((u32)f2bf(o2) << 16);
    }
    // K: 8 heads x 32 pairs == 256 threads; head-major layout [kv][t][64]
    {
        int kv = tid >> 5, i = tid & 31;
        float2 ab = pair(QD + kv * 64 + 2 * i);
        float o1 = ab.x * cs[i] - ab.y * sn[i];
        float o2 = ab.y * cs[i] + ab.x * sn[i];
        *(u32*)(kr + ((long)kv * TTOK + t) * HD + 2 * i) = (u32)f2bf(o1) | ((u32)f2bf(o2) << 16);
    }
    // V: 8 heads x 64 = 256 u32; head-major [kv][t][64]
    {
        int kv = tid >> 5, d2 = tid & 31;
        float2 ab = pair(QD + 512 + kv * 64 + 2 * d2);
        *(u32*)(vr + ((long)kv * TTOK + t) * HD + 2 * d2) = (u32)f2bf(ab.x) | ((u32)f2bf(ab.y) << 16);
    }
}

// ---------------- MFMA sliding-window attention with sink ----------------
__global__ __launch_bounds__(256, 2) void attn_kernel(const u16* __restrict__ qr,
                                                      const u16* __restrict__ kr,
                                                      const u16* __restrict__ vr,
                                                      const float* __restrict__ sinks,
                                                      u16* __restrict__ o) {
    const int t0  = blockIdx.x * 16;
    const int h   = blockIdx.y;
    const int qhg = blockIdx.z;
    const int tid = threadIdx.x;
    const int lane = tid & 63, wv = tid >> 6;
    __shared__ __align__(16) u16 ks[144][72];    // K rows [key][64+pad]
    __shared__ __align__(16) u16 Vt[64][168];    // V^T [d][key], cols 144..159 zero
    __shared__ __align__(16) u16 P [4][16][168]; // per-wave P [token][key], cols 144..159 zero
    const u16* kb = kr + (long)h * TTOK * HD;
    const u16* vb = vr + (long)h * TTOK * HD;

    // stage K rows (coalesced)
    #pragma unroll
    for (int i = 0; i < 5; ++i) {
        int idx = i * 256 + tid;
        if (idx < 144 * 8) {
            int rr = idx >> 3, c = idx & 7;
            int tk = t0 - 128 + rr;
            int tks = tk < 0 ? 0 : tk;          // clamped; masked later
            *(uint4*)&ks[rr][c * 8] = *(const uint4*)(kb + (long)tks * HD + c * 8);
        }
    }
    // stage V transposed: thread -> one key, 8 dims per pass
    #pragma unroll
    for (int c4 = 0; c4 < 8; ++c4) {
        if (tid < 144) {
            int tk = t0 - 128 + tid;
            int tks = tk < 0 ? 0 : tk;
            uint4 v4 = *(const uint4*)(vb + (long)tks * HD + c4 * 8);
            int d0 = c4 * 8;
            Vt[d0+0][tid] = (u16)(v4.x & 0xffff); Vt[d0+1][tid] = (u16)(v4.x >> 16);
            Vt[d0+2][tid] = (u16)(v4.y & 0xffff); Vt[d0+3][tid] = (u16)(v4.y >> 16);
            Vt[d0+4][tid] = (u16)(v4.z & 0xffff); Vt[d0+5][tid] = (u16)(v4.z >> 16);
            Vt[d0+6][tid] = (u16)(v4.w & 0xffff); Vt[d0+7][tid] = (u16)(v4.w >> 16);
        }
    }
    if (tid < 128) {
        *(uint4*)&Vt[tid >> 1][144 + (tid & 1) * 8] = uint4{0, 0, 0, 0};
    }
    if (lane < 32) {
        *(uint4*)&P[wv][lane >> 1][144 + (lane & 1) * 8] = uint4{0, 0, 0, 0};
    }
    __syncthreads();

    const int qh   = qhg * 4 + wv;
    const int head = h * QMULT + qh;
    const int fr = lane & 15, fk = (lane >> 4) * 8;
    const int cr = (lane >> 4) * 4;

    const u16* qrow = qr + (long)(t0 + fr) * QD + head * HD;
    bf16x8 qf0 = *(const bf16x8*)(qrow + fk);
    bf16x8 qf1 = *(const bf16x8*)(qrow + 32 + fk);

    const int kmin = 128 - t0;          // kk >= kmin <=> key token >= 0
    float lsum[4] = {0.f, 0.f, 0.f, 0.f};

    for (int nt = 0; nt < 9; ++nt) {
        bf16x8 b0 = *(const bf16x8*)&ks[nt * 16 + fr][fk];
        bf16x8 b1 = *(const bf16x8*)&ks[nt * 16 + fr][32 + fk];
        f32x4 s = f32x4{0.f, 0.f, 0.f, 0.f};
        s = __builtin_amdgcn_mfma_f32_16x16x32_bf16(qf0, b0, s, 0, 0, 0);
        s = __builtin_amdgcn_mfma_f32_16x16x32_bf16(qf1, b1, s, 0, 0, 0);
        const int kk = nt * 16 + fr;    // C-layout col = lane&15
        #pragma unroll
        for (int r = 0; r < 4; ++r) {
            int row = cr + r;           // token index within tile
            bool valid = (kk >= row) && (kk <= row + 128) && (kk >= kmin);
            float p = valid ? __expf(s[r] * 0.125f) : 0.0f;
            lsum[r] += p;
            P[wv][row][kk] = f2bf(p);
        }
    }

    f32x4 oacc[4];
    #pragma unroll
    for (int dt = 0; dt < 4; ++dt) oacc[dt] = f32x4{0.f, 0.f, 0.f, 0.f};
    #pragma unroll
    for (int k5 = 0; k5 < 5; ++k5) {
        const int k0 = k5 * 32;
        bf16x8 pa = *(const bf16x8*)&P[wv][fr][k0 + fk];
        #pragma unroll
        for (int dt = 0; dt < 4; ++dt) {
            bf16x8 vf = *(const bf16x8*)&Vt[dt * 16 + fr][k0 + fk];
            oacc[dt] = __builtin_amdgcn_mfma_f32_16x16x32_bf16(pa, vf, oacc[dt], 0, 0, 0);
        }
    }

    #pragma unroll
    for (int r = 0; r < 4; ++r) {
        float v = lsum[r];
        v += __shfl_xor(v, 1);
        v += __shfl_xor(v, 2);
        v += __shfl_xor(v, 4);
        v += __shfl_xor(v, 8);
        lsum[r] = v;
    }
    const float sk = exp2f(sinks[head]);
    float inv[4];
    #pragma unroll
    for (int r = 0; r < 4; ++r) inv[r] = 1.0f / (lsum[r] + sk);

    #pragma unroll
    for (int dt = 0; dt < 4; ++dt) {
        #pragma unroll
        for (int r = 0; r < 4; ++r) {
            o[(long)(t0 + cr + r) * QD + head * HD + dt * 16 + fr] = f2bf(oacc[dt][r] * inv[r]);
        }
    }
}

// ---------------- reduce GEMM2 partials + bias + residual -> out ----------------
__global__ __launch_bounds__(256) void reduce2_kernel(const u16* __restrict__ p2a,
                                                      const u16* __restrict__ p2b,
                                                      const float* __restrict__ x,
                                                      const float* __restrict__ b_out,
                                                      float* __restrict__ out) {
    const int row = blockIdx.y;
    const int c4 = blockIdx.x * 256 + threadIdx.x;   // float4 index within row
    if (c4 >= 720) return;
    const int col = c4 * 4;
    ushort4 ua = *(const ushort4*)(p2a + (long)row * NPAD + col);
    ushort4 ub = *(const ushort4*)(p2b + (long)row * NPAD + col);
    float4 xv = *(const float4*)(x + (long)row * HIDDEN + col);
    float4 bv = *(const float4*)(b_out + col);
    float4 o;
    o.x = xv.x + bv.x + __uint_as_float((u32)ua.x << 16) + __uint_as_float((u32)ub.x << 16);
    o.y = xv.y + bv.y + __uint_as_float((u32)ua.y << 16) + __uint_as_float((u32)ub.y << 16);
    o.z = xv.z + bv.z + __uint_as_float((u32)ua.z << 16) + __uint_as_float((u32)ub.z << 16);
    o.w = xv.w + bv.w + __uint_as_float((u32)ua.w << 16) + __uint_as_float((u32)ub.w << 16);
    *(float4*)(out + (long)row * HIDDEN + col) = o;
}

// ---------------- launcher ----------------
extern "C" void kernel_launch(void* const* d_in, const int* in_sizes, int n_in,
                              void* d_out, int out_size, void* d_ws, size_t ws_size,
                              hipStream_t stream) {
    const float* x      = (const float*)d_in[0];
    const float* nscale = (const float*)d_in[1];
    const float* w_qkv  = (const float*)d_in[2];
    const float* b_qkv  = (const float*)d_in[3];
    const float* sinks  = (const float*)d_in[4];
    const float* w_out  = (const float*)d_in[5];
    const float* b_out  = (const float*)d_in[6];
    float* out = (float*)d_out;

    static int smem_set = 0;
    if (!smem_set) {
        hipFuncSetAttribute((const void*)gemm_bt_8ph,
                            hipFuncAttributeMaxDynamicSharedMemorySize, 131072);
        smem_set = 1;
    }

    const size_t slab = (size_t)TTOK * QKVD * 2;               // 21.0 MB per partial
    const size_t fixed = ((size_t)QKVD * HIDDEN * 2)           // wqkv_bf 29.5
                       + ((size_t)NPAD * QD * 2)               // wout_bf 24.1
                       + ((size_t)TTOK * HIDDEN * 2)           // h 11.8
                       + ((size_t)TTOK * QD * 2)               // qrot 16.8
                       + 4096;                                 // align slack
    const int gs1 = (fixed + 3 * slab <= ws_size) ? 3 : 2;     // GEMM1 split-K ways

    char* ws = (char*)d_ws;
    size_t off = 0;
    auto alloc = [&](size_t bytes) { void* p = ws + off; off += (bytes + 255) & ~(size_t)255; return p; };
    u16* wqkv_bf = (u16*)alloc((size_t)QKVD * HIDDEN * 2);     // 29.5 MB
    u16* wout_bf = (u16*)alloc((size_t)NPAD * QD * 2);         // 24.1 MB
    u16* h       = (u16*)alloc((size_t)TTOK * HIDDEN * 2);     // 11.8 MB
    u16* p1      = (u16*)alloc((size_t)gs1 * slab);            // gs1 x 21.0 MB
    u16* qrot    = (u16*)alloc((size_t)TTOK * QD * 2);         // 16.8 MB
    // aliases (dead-after analysis):
    u16* attn = wqkv_bf;                       // wqkv_bf dead after gemm1 (16.8 MB)
    u16* krot = wqkv_bf + (size_t)TTOK * QD;   // wqkv tail: +2.1 MB
    u16* vrot = krot + (size_t)NKV * TTOK * HD;// +2.1 MB (total 21.0 <= 29.5 OK)
    u16* p2   = p1;                            // p1 dead after rope; 24.1 <= gs1*21 OK

    prep_kernel<<<PREP_QKV_BLOCKS + PREP_RMS_BLOCKS, 256, 0, stream>>>(
        w_qkv, wqkv_bf, x, nscale, h);
    // GEMM1: split-K z=gs1 (3 -> 480 blocks, 93.75% fill) + 1 filler z-slice
    // (w_out cvt) that backfills the tail round. Uneven z=2 split (1472/1408)
    // handled by in-kernel NT clamp.
    const int ks1 = (gs1 == 3) ? (HIDDEN / 3) : 1472;
    gemm_bt_8ph<<<dim3(QKVD / 256, TTOK / 256, gs1 + 1), 512, 131072, stream>>>(
        h, wqkv_bf, p1, QKVD, HIDDEN, ks1, QKVD - 1, QKVD, gs1, w_out, wout_bf);
    rope_kernel<<<TTOK, 256, 0, stream>>>(p1, b_qkv, qrot, krot, vrot, gs1);
    attn_kernel<<<dim3(TTOK / 16, NKV, 2), 256, 0, stream>>>(qrot, krot, vrot, sinks, attn);
    // GEMM2: split-K z=2, 12x8x2 = 192 blocks (single round)
    gemm_bt_8ph<<<dim3((NPAD + 255) / 256, TTOK / 256, 2), 512, 131072, stream>>>(
        attn, wout_bf, p2, NPAD, QD, QD / 2, NPAD - 1, NPAD, 2, nullptr, nullptr);
    reduce2_kernel<<<dim3(3, TTOK), 256, 0, stream>>>(
        p2, p2 + (size_t)TTOK * NPAD, x, b_out, out);
}

// Round 5
// 336.979 us; speedup vs baseline: 1.0563x; 1.0563x over previous
//
#include <hip/hip_runtime.h>
#include <math.h>

typedef unsigned short u16;
typedef unsigned int   u32;
using f32x4  = __attribute__((ext_vector_type(4))) float;
using bf16x8 = __attribute__((ext_vector_type(8))) __bf16;

#define HIDDEN   2880
#define QKVD     5120
#define QD       4096
#define TTOK     2048
#define NKV      8
#define QMULT    8
#define HD       64
#define NPAD     2944   // w_out rows padded to 23*128 (GEMM2 store-guards col<2944)

// prep grid partition (w_out cvt rides in GEMM1's idle CUs)
#define PREP_QKV_BLOCKS  14400   // QKVD*HIDDEN/4/256
#define PREP_RMS_BLOCKS  2048

static __device__ __forceinline__ float bflo(u32 u){ return __uint_as_float(u << 16); }
static __device__ __forceinline__ float bfhi(u32 u){ return __uint_as_float(u & 0xffff0000u); }
static __device__ __forceinline__ u16 f2bf(float f){
    u32 u = __float_as_uint(f);
    u32 r = (u + 0x7fffu + ((u >> 16) & 1u)) >> 16;
    return (u16)r;
}

static __device__ __forceinline__ void glds16(const void* g, void* l) {
    __builtin_amdgcn_global_load_lds(
        (__attribute__((address_space(1))) void*)g,
        (__attribute__((address_space(3))) void*)l,
        16, 0, 0);
}

// R5 MECHANICS (the whole round): R1-R4 used asm("s_barrier":::"memory").
// The "memory" clobber makes the compiler's waitcnt pass treat the asm as a
// memory access -> it emits s_waitcnt vmcnt(0) lgkmcnt(0) BEFORE EVERY barrier.
// That nullified all counted-vmcnt discipline (R1 vmcnt4 -> R2 vmcnt8 moved
// nothing) and forced lockstep read|MFMA alternation (pipes additive:
// 2483+2304 = 4880 cy/tile measured across 3 different schedules).
// Fix = m201-template mechanics: RAW builtin s_barrier (no IR fence, no drain),
// explicit counted waits, sched_barrier(0) pins (rule #18).
#define BARB()  __builtin_amdgcn_s_barrier()
#define SB0()   __builtin_amdgcn_sched_barrier(0)
#define LGKM0() do { asm volatile("s_waitcnt lgkmcnt(0)"); SB0(); } while (0)
#define VMW(N)  do { SB0(); asm volatile("s_waitcnt vmcnt(" #N ")"); SB0(); } while (0)

// ---------------- fused prep: w_qkv cvt | rmsnorm ----------------
__global__ __launch_bounds__(256) void prep_kernel(const float* __restrict__ w_qkv,
                                                   u16* __restrict__ wqkv_bf,
                                                   const float* __restrict__ x,
                                                   const float* __restrict__ scale,
                                                   u16* __restrict__ h) {
    const int b = blockIdx.x;
    const int tid = threadIdx.x;
    if (b < PREP_QKV_BLOCKS) {
        int i = b * 256 + tid;
        float4 f = ((const float4*)w_qkv)[i];
        ushort4 o;
        o.x = f2bf(f.x); o.y = f2bf(f.y); o.z = f2bf(f.z); o.w = f2bf(f.w);
        ((ushort4*)wqkv_bf)[i] = o;
    } else {
        const int t = b - PREP_QKV_BLOCKS;
        const float4* xr = (const float4*)(x + (long)t * HIDDEN);
        float4 v[3];
        float ss = 0.f;
        #pragma unroll
        for (int it = 0; it < 3; ++it) {
            int i4 = tid + it * 256;
            if (i4 < 720) {
                v[it] = xr[i4];
                ss += v[it].x*v[it].x + v[it].y*v[it].y + v[it].z*v[it].z + v[it].w*v[it].w;
            }
        }
        #pragma unroll
        for (int off = 32; off > 0; off >>= 1) ss += __shfl_down(ss, off);
        __shared__ float red[4];
        if ((tid & 63) == 0) red[tid >> 6] = ss;
        __syncthreads();
        float tot = red[0] + red[1] + red[2] + red[3];
        float rr = rsqrtf(tot * (1.0f / HIDDEN) + 1e-5f);
        ushort4* hr = (ushort4*)(h + (long)t * HIDDEN);
        #pragma unroll
        for (int it = 0; it < 3; ++it) {
            int i4 = tid + it * 256;
            if (i4 < 720) {
                float4 s4 = ((const float4*)scale)[i4];
                ushort4 o;
                o.x = f2bf(v[it].x * rr * s4.x);
                o.y = f2bf(v[it].y * rr * s4.y);
                o.z = f2bf(v[it].z * rr * s4.z);
                o.w = f2bf(v[it].w * rr * s4.w);
                hr[i4] = o;
            }
        }
    }
}

// ---------------- 8-phase 256x256/BK=64 GEMM: C = A[M,K] @ B[N,K]^T (bf16) -------
// Structure = R2's (best measured: 89.2us); ONLY the barrier/wait mechanics
// changed this round (see BARB/LGKM0/VMW above). 512 thr = 8 waves (2M x 4N),
// wave tile 128x64, acc[8][4] f32x4.
// LDS 160 KB: A triple-buffered [3][256][64] (96 KB) + B double [2][256][64].
// Swizzle (rule #21): global_load_lds writes LINEARLY; per-lane GLOBAL source
// 16B-granule XOR'd with (row&7); ds_read applies the same XOR (folds into
// per-lane constants off0/off1). Bank conflicts measured 0 (R1-R4).
// vmcnt: one counted vmcnt(8) per K-tile, never 0 mid-loop.
//   Drain proof: loads issued during tile t = A(t+2)x4 + B(t+2)x4 = 8; waiting
//   vmcnt(8) at end of t forces all of A(t+1),B(t+1) landed before tile t+1;
//   the following barrier propagates that across waves.
// Slot safety: each stage is issued >=1 barrier after the previous occupant's
// last ds_read (all bq reads of tile t happen in ph1; stageB(t+2) into slot
// t&1 issues in ph2/ph3, after ph1's post-MFMA barrier).
// Filler z-slices (blockIdx.z >= nz_gemm) do the w_out f32->bf16+pad cvt on
// GEMM1's 96 idle CUs.

#define LOAD_AQ(MH) do { \
    aq[0][0] = *(const bf16x8*)(aS + (2*(MH)+0)*2048 + off0); \
    aq[0][1] = *(const bf16x8*)(aS + (2*(MH)+0)*2048 + off1); \
    aq[1][0] = *(const bf16x8*)(aS + (2*(MH)+1)*2048 + off0); \
    aq[1][1] = *(const bf16x8*)(aS + (2*(MH)+1)*2048 + off1); \
} while (0)

#define MFMA_Q(MH) do { \
    __builtin_amdgcn_s_setprio(1); \
    _Pragma("unroll") \
    for (int i2_ = 0; i2_ < 2; ++i2_) { \
        _Pragma("unroll") \
        for (int ni_ = 0; ni_ < 4; ++ni_) { \
            acc[2*(MH)+i2_][ni_] = __builtin_amdgcn_mfma_f32_16x16x32_bf16(aq[i2_][0], bq[ni_][0], acc[2*(MH)+i2_][ni_], 0, 0, 0); \
            acc[2*(MH)+i2_][ni_] = __builtin_amdgcn_mfma_f32_16x16x32_bf16(aq[i2_][1], bq[ni_][1], acc[2*(MH)+i2_][ni_], 0, 0, 0); \
        } \
    } \
    __builtin_amdgcn_s_setprio(0); \
} while (0)

__global__ __launch_bounds__(512, 2) void gemm_bt_8ph(const u16* __restrict__ A,
                                                      const u16* __restrict__ B,
                                                      u16* __restrict__ C0,
                                                      int N, int K, int ksplit,
                                                      int blimit, int colmax,
                                                      int nz_gemm,
                                                      const float* __restrict__ wout_src,
                                                      u16* __restrict__ wout_dst) {
    const int tid  = threadIdx.x;

    if ((int)blockIdx.z >= nz_gemm) {
        // ---- filler blocks: w_out cvt+pad [HIDDEN][QD] f32 -> [NPAD][QD] bf16 ----
        const long nb = (long)gridDim.x * gridDim.y;
        long bidx = (long)blockIdx.y * gridDim.x + blockIdx.x;
        long i = bidx * 512 + tid;
        const long tot = (long)NPAD * QD / 4;
        const long stride = nb * 512;
        for (; i < tot; i += stride) {
            long idx = i * 4;
            int row = (int)(idx >> 12);
            int col = (int)(idx & 4095);
            ushort4 o;
            if (row < HIDDEN) {
                float4 f = *(const float4*)(wout_src + (long)row * QD + col);
                o.x = f2bf(f.x); o.y = f2bf(f.y); o.z = f2bf(f.z); o.w = f2bf(f.w);
            } else {
                o.x = 0; o.y = 0; o.z = 0; o.w = 0;
            }
            ((ushort4*)wout_dst)[i] = o;
        }
        return;
    }

    extern __shared__ u16 smem[];
    u16* const smA = smem;                  // [3][256][64] bf16 (32 KB/slot)
    u16* const smB = smem + 3 * 256 * 64;   // byte 98304, [2][256][64]
    const int lane = tid & 63;
    const int wv   = tid >> 6;              // wave 0..7
    const int wm   = wv >> 2;               // 0..1 (M)
    const int wn   = wv & 3;                // 0..3 (N)
    const long m0  = (long)blockIdx.y * 256;
    const long n0  = (long)blockIdx.x * 256;
    const int kbase = blockIdx.z * ksplit;
    int krem = K - kbase; if (krem > ksplit) krem = ksplit;
    const int NT   = krem >> 6;             // K-tiles of 64
    u16* C = C0 + (size_t)blockIdx.z * ((size_t)TTOK * N);

    // staging: per-thread 16B granule; source column pre-swizzled (rule #21 pair)
    const int srow = tid >> 3;                              // 0..63
    const int sg8  = ((tid & 7) ^ (srow & 7)) << 3;         // src elem offset
    // fragment reads: swizzle folds to per-lane constants (row&7 == lane&7)
    const int fr   = lane & 15;
    const int off0 = ((lane >> 4) << 4) ^ ((lane & 7) << 4);
    const int off1 = off0 ^ 64;
    const char* aR = (const char*)smA + (wm * 128 + fr) * 128;
    const char* bR = (const char*)smB + (wn * 64  + fr) * 128;

    f32x4 acc[8][4];
    #pragma unroll
    for (int i = 0; i < 8; ++i)
        #pragma unroll
        for (int j = 0; j < 4; ++j) acc[i][j] = f32x4{0.f, 0.f, 0.f, 0.f};

    const u16* Asrc = A + (m0 + srow) * (long)K + kbase + sg8;
    auto stageA = [&](int t, int slot) {
        char* dst = (char*)smA + slot * 32768 + (wv * 8) * 128;
        const u16* src = Asrc + t * 64;
        #pragma unroll
        for (int hj = 0; hj < 4; ++hj)
            glds16(src + (size_t)(hj * 64) * K, dst + hj * 64 * 128);
    };
    auto stageB = [&](int t, int h) {
        char* dst = (char*)smB + (t & 1) * 32768 + (h * 128 + wv * 8) * 128;
        #pragma unroll
        for (int j = 0; j < 2; ++j) {
            long r = n0 + h * 128 + j * 64 + srow;
            if (r > blimit) r = blimit;   // clamp into zero-padded rows
            glds16(B + (size_t)r * K + kbase + t * 64 + sg8, dst + j * 64 * 128);
        }
    };

    // prologue: A(0)->slot0, B(0); A(1)->slot1, B(1). 16 loads; vmcnt(8) leaves
    // only the newest 8 (A1,B1) outstanding => A0,B0 landed.
    stageA(0, 0);
    stageB(0, 0); stageB(0, 1);
    if (NT > 1) {
        stageA(1, 1); stageB(1, 0); stageB(1, 1);
        VMW(8);
    } else {
        VMW(0);
    }
    BARB();

    int sA = 0;                             // A slot of tile t (t % 3)
    for (int t = 0; t < NT; ++t) {
        const char* aS = aR + sA * 32768;
        const char* bS = bR + (t & 1) * 32768;
        int sA2 = sA + 2; if (sA2 >= 3) sA2 -= 3;   // slot for t+2
        bf16x8 bq[4][2], aq[2][2];
        // ---- ph1: all B frags + A half 0; prefetch A(t+2) (3rd slot: distinct
        //      from live slots t, t+1; old occupant's reads ended last tile)
        #pragma unroll
        for (int ni = 0; ni < 4; ++ni) {
            bq[ni][0] = *(const bf16x8*)(bS + ni * 2048 + off0);
            bq[ni][1] = *(const bf16x8*)(bS + ni * 2048 + off1);
        }
        LOAD_AQ(0);
        if (t + 2 < NT) stageA(t + 2, sA2);
        BARB();
        LGKM0();
        MFMA_Q(0);
        BARB();
        // ---- ph2: A half 1; prefetch B(t+2) half0 (slot t&1: all bq reads of
        //      tile t completed before ph1's post-MFMA barrier)
        LOAD_AQ(1);
        if (t + 2 < NT) stageB(t + 2, 0);
        BARB();
        LGKM0();
        MFMA_Q(1);
        BARB();
        // ---- ph3: A half 2; prefetch B(t+2) half1
        LOAD_AQ(2);
        if (t + 2 < NT) stageB(t + 2, 1);
        BARB();
        LGKM0();
        MFMA_Q(2);
        BARB();
        // ---- ph4: A half 3; K-tile checkpoint (counted, never 0 mid-loop)
        LOAD_AQ(3);
        BARB();
        LGKM0();
        MFMA_Q(3);
        if (t + 2 < NT)      VMW(8);
        else if (t + 1 < NT) VMW(0);
        BARB();
        sA = (sA == 2) ? 0 : sA + 1;
    }

    // epilogue: C/D layout col=lane&15, row=(lane>>4)*4+reg  [m89-verified]
    const int cr = (lane >> 4) * 4;
    const int cc = lane & 15;
    #pragma unroll
    for (int ni = 0; ni < 4; ++ni) {
        long col = n0 + wn * 64 + ni * 16 + cc;
        if (col < colmax) {
            #pragma unroll
            for (int mi = 0; mi < 8; ++mi) {
                long row = m0 + wm * 128 + mi * 16 + cr;
                #pragma unroll
                for (int r2 = 0; r2 < 4; ++r2)
                    C[(row + r2) * (long)N + col] = f2bf(acc[mi][ni][r2]);
            }
        }
    }
}

// ------- RoPE (YaRN), consumes nsplit GEMM1 split-K partials + bias -------------
__global__ __launch_bounds__(256) void rope_kernel(const u16* __restrict__ p1,
                                                   const float* __restrict__ b_qkv,
                                                   u16* __restrict__ qr,
                                                   u16* __restrict__ kr,
                                                   u16* __restrict__ vr,
                                                   int nsplit) {
    const int t = blockIdx.x;
    const int tid = threadIdx.x;
    __shared__ float cs[32], sn[32];
    if (tid < 32) {
        float fi = (float)tid;
        float freq   = exp2f(17.1946032f * (fi * (1.0f / 32.0f)));   // 150000^(i/32)
        float interp = 1.0f / (32.0f * freq);
        float extra  = 1.0f / freq;
        float ramp   = (fi - 8.0927802f) * (1.0f / (17.3980220f - 8.0927802f));
        float rc     = fminf(fmaxf(ramp, 0.0f), 1.0f);               // = 1 - mask
        float invf   = interp * rc + extra * (1.0f - rc);
        float ang    = (float)t * invf;
        cs[tid] = cosf(ang) * 1.3465736f;                            // * concentration
        sn[tid] = sinf(ang) * 1.3465736f;
    }
    __syncthreads();
    const u16* rowA = p1 + (long)t * QKVD;
    auto pair = [&](int col) -> float2 {
        float2 bb = *(const float2*)(b_qkv + col);
        float a = bb.x, b = bb.y;
        for (int s = 0; s < nsplit; ++s) {
            u32 u = *(const u32*)(rowA + (size_t)s * TTOK * QKVD + col);
            a += bflo(u); b += bfhi(u);
        }
        return make_float2(a, b);
    };
    // Q: 64 heads x 32 pairs
    for (int p = tid; p < 2048; p += 256) {
        int hd2 = p >> 5, i = p & 31;
        float2 ab = pair(hd2 * 64 + 2 * i);
        float o1 = ab.x * cs[i] - ab.y * sn[i];
        float o2 = ab.y * cs[i] + ab.x * sn[i];
        *(u32*)(qr + (long)t * QD + hd2 * 64 + 2 * i) = (u32)f2bf(o1) | ((u32)f2bf(o2) << 16);
    }
    // K: 8 heads x 32 pairs == 256 threads; head-major layout [kv][t][64]
    {
        int kv = tid >> 5, i = tid & 31;
        float2 ab = pair(QD + kv * 64 + 2 * i);
        float o1 = ab.x * cs[i] - ab.y * sn[i];
        float o2 = ab.y * cs[i] + ab.x * sn[i];
        *(u32*)(kr + ((long)kv * TTOK + t) * HD + 2 * i) = (u32)f2bf(o1) | ((u32)f2bf(o2) << 16);
    }
    // V: 8 heads x 64 = 256 u32; head-major [kv][t][64]
    {
        int kv = tid >> 5, d2 = tid & 31;
        float2 ab = pair(QD + 512 + kv * 64 + 2 * d2);
        *(u32*)(vr + ((long)kv * TTOK + t) * HD + 2 * d2) = (u32)f2bf(ab.x) | ((u32)f2bf(ab.y) << 16);
    }
}

// ---------------- MFMA sliding-window attention with sink ----------------
__global__ __launch_bounds__(256, 2) void attn_kernel(const u16* __restrict__ qr,
                                                      const u16* __restrict__ kr,
                                                      const u16* __restrict__ vr,
                                                      const float* __restrict__ sinks,
                                                      u16* __restrict__ o) {
    const int t0  = blockIdx.x * 16;
    const int h   = blockIdx.y;
    const int qhg = blockIdx.z;
    const int tid = threadIdx.x;
    const int lane = tid & 63, wv = tid >> 6;
    __shared__ __align__(16) u16 ks[144][72];    // K rows [key][64+pad]
    __shared__ __align__(16) u16 Vt[64][168];    // V^T [d][key], cols 144..159 zero
    __shared__ __align__(16) u16 P [4][16][168]; // per-wave P [token][key], cols 144..159 zero
    const u16* kb = kr + (long)h * TTOK * HD;
    const u16* vb = vr + (long)h * TTOK * HD;

    // stage K rows (coalesced)
    #pragma unroll
    for (int i = 0; i < 5; ++i) {
        int idx = i * 256 + tid;
        if (idx < 144 * 8) {
            int rr = idx >> 3, c = idx & 7;
            int tk = t0 - 128 + rr;
            int tks = tk < 0 ? 0 : tk;          // clamped; masked later
            *(uint4*)&ks[rr][c * 8] = *(const uint4*)(kb + (long)tks * HD + c * 8);
        }
    }
    // stage V transposed: thread -> one key, 8 dims per pass
    #pragma unroll
    for (int c4 = 0; c4 < 8; ++c4) {
        if (tid < 144) {
            int tk = t0 - 128 + tid;
            int tks = tk < 0 ? 0 : tk;
            uint4 v4 = *(const uint4*)(vb + (long)tks * HD + c4 * 8);
            int d0 = c4 * 8;
            Vt[d0+0][tid] = (u16)(v4.x & 0xffff); Vt[d0+1][tid] = (u16)(v4.x >> 16);
            Vt[d0+2][tid] = (u16)(v4.y & 0xffff); Vt[d0+3][tid] = (u16)(v4.y >> 16);
            Vt[d0+4][tid] = (u16)(v4.z & 0xffff); Vt[d0+5][tid] = (u16)(v4.z >> 16);
            Vt[d0+6][tid] = (u16)(v4.w & 0xffff); Vt[d0+7][tid] = (u16)(v4.w >> 16);
        }
    }
    if (tid < 128) {
        *(uint4*)&Vt[tid >> 1][144 + (tid & 1) * 8] = uint4{0, 0, 0, 0};
    }
    if (lane < 32) {
        *(uint4*)&P[wv][lane >> 1][144 + (lane & 1) * 8] = uint4{0, 0, 0, 0};
    }
    __syncthreads();

    const int qh   = qhg * 4 + wv;
    const int head = h * QMULT + qh;
    const int fr = lane & 15, fk = (lane >> 4) * 8;
    const int cr = (lane >> 4) * 4;

    const u16* qrow = qr + (long)(t0 + fr) * QD + head * HD;
    bf16x8 qf0 = *(const bf16x8*)(qrow + fk);
    bf16x8 qf1 = *(const bf16x8*)(qrow + 32 + fk);

    const int kmin = 128 - t0;          // kk >= kmin <=> key token >= 0
    float lsum[4] = {0.f, 0.f, 0.f, 0.f};

    for (int nt = 0; nt < 9; ++nt) {
        bf16x8 b0 = *(const bf16x8*)&ks[nt * 16 + fr][fk];
        bf16x8 b1 = *(const bf16x8*)&ks[nt * 16 + fr][32 + fk];
        f32x4 s = f32x4{0.f, 0.f, 0.f, 0.f};
        s = __builtin_amdgcn_mfma_f32_16x16x32_bf16(qf0, b0, s, 0, 0, 0);
        s = __builtin_amdgcn_mfma_f32_16x16x32_bf16(qf1, b1, s, 0, 0, 0);
        const int kk = nt * 16 + fr;    // C-layout col = lane&15
        #pragma unroll
        for (int r = 0; r < 4; ++r) {
            int row = cr + r;           // token index within tile
            bool valid = (kk >= row) && (kk <= row + 128) && (kk >= kmin);
            float p = valid ? __expf(s[r] * 0.125f) : 0.0f;
            lsum[r] += p;
            P[wv][row][kk] = f2bf(p);
        }
    }

    f32x4 oacc[4];
    #pragma unroll
    for (int dt = 0; dt < 4; ++dt) oacc[dt] = f32x4{0.f, 0.f, 0.f, 0.f};
    #pragma unroll
    for (int k5 = 0; k5 < 5; ++k5) {
        const int k0 = k5 * 32;
        bf16x8 pa = *(const bf16x8*)&P[wv][fr][k0 + fk];
        #pragma unroll
        for (int dt = 0; dt < 4; ++dt) {
            bf16x8 vf = *(const bf16x8*)&Vt[dt * 16 + fr][k0 + fk];
            oacc[dt] = __builtin_amdgcn_mfma_f32_16x16x32_bf16(pa, vf, oacc[dt], 0, 0, 0);
        }
    }

    #pragma unroll
    for (int r = 0; r < 4; ++r) {
        float v = lsum[r];
        v += __shfl_xor(v, 1);
        v += __shfl_xor(v, 2);
        v += __shfl_xor(v, 4);
        v += __shfl_xor(v, 8);
        lsum[r] = v;
    }
    const float sk = exp2f(sinks[head]);
    float inv[4];
    #pragma unroll
    for (int r = 0; r < 4; ++r) inv[r] = 1.0f / (lsum[r] + sk);

    #pragma unroll
    for (int dt = 0; dt < 4; ++dt) {
        #pragma unroll
        for (int r = 0; r < 4; ++r) {
            o[(long)(t0 + cr + r) * QD + head * HD + dt * 16 + fr] = f2bf(oacc[dt][r] * inv[r]);
        }
    }
}

// ---------------- reduce GEMM2 partials + bias + residual -> out ----------------
__global__ __launch_bounds__(256) void reduce2_kernel(const u16* __restrict__ p2a,
                                                      const u16* __restrict__ p2b,
                                                      const float* __restrict__ x,
                                                      const float* __restrict__ b_out,
                                                      float* __restrict__ out) {
    const int row = blockIdx.y;
    const int c4 = blockIdx.x * 256 + threadIdx.x;   // float4 index within row
    if (c4 >= 720) return;
    const int col = c4 * 4;
    ushort4 ua = *(const ushort4*)(p2a + (long)row * NPAD + col);
    ushort4 ub = *(const ushort4*)(p2b + (long)row * NPAD + col);
    float4 xv = *(const float4*)(x + (long)row * HIDDEN + col);
    float4 bv = *(const float4*)(b_out + col);
    float4 o;
    o.x = xv.x + bv.x + __uint_as_float((u32)ua.x << 16) + __uint_as_float((u32)ub.x << 16);
    o.y = xv.y + bv.y + __uint_as_float((u32)ua.y << 16) + __uint_as_float((u32)ub.y << 16);
    o.z = xv.z + bv.z + __uint_as_float((u32)ua.z << 16) + __uint_as_float((u32)ub.z << 16);
    o.w = xv.w + bv.w + __uint_as_float((u32)ua.w << 16) + __uint_as_float((u32)ub.w << 16);
    *(float4*)(out + (long)row * HIDDEN + col) = o;
}

// ---------------- launcher ----------------
extern "C" void kernel_launch(void* const* d_in, const int* in_sizes, int n_in,
                              void* d_out, int out_size, void* d_ws, size_t ws_size,
                              hipStream_t stream) {
    const float* x      = (const float*)d_in[0];
    const float* nscale = (const float*)d_in[1];
    const float* w_qkv  = (const float*)d_in[2];
    const float* b_qkv  = (const float*)d_in[3];
    const float* sinks  = (const float*)d_in[4];
    const float* w_out  = (const float*)d_in[5];
    const float* b_out  = (const float*)d_in[6];
    float* out = (float*)d_out;

    static int smem_set = 0;
    if (!smem_set) {
        hipFuncSetAttribute((const void*)gemm_bt_8ph,
                            hipFuncAttributeMaxDynamicSharedMemorySize, 163840);
        smem_set = 1;
    }

    char* ws = (char*)d_ws;
    size_t off = 0;
    auto alloc = [&](size_t bytes) { void* p = ws + off; off += (bytes + 255) & ~(size_t)255; return p; };
    const size_t p1_bytes  = (size_t)TTOK * QKVD * 2;          // 21.0 MB (GEMM1 out)
    const size_t p2_bytes  = (size_t)2 * TTOK * NPAD * 2;      // 24.1 MB (GEMM2 partials)
    u16* wqkv_bf = (u16*)alloc((size_t)QKVD * HIDDEN * 2);     // 29.5 MB
    u16* wout_bf = (u16*)alloc((size_t)NPAD * QD * 2);         // 24.1 MB
    u16* h       = (u16*)alloc((size_t)TTOK * HIDDEN * 2);     // 11.8 MB
    u16* p1      = (u16*)alloc(p1_bytes > p2_bytes ? p1_bytes : p2_bytes);
    u16* qrot    = (u16*)alloc((size_t)TTOK * QD * 2);         // 16.8 MB
    // aliases (dead-after analysis):
    u16* attn = wqkv_bf;                       // wqkv_bf dead after gemm1 (16.8 MB)
    u16* krot = wqkv_bf + (size_t)TTOK * QD;   // wqkv tail: +2.1 MB
    u16* vrot = krot + (size_t)NKV * TTOK * HD;// +2.1 MB (total 21.0 <= 29.5 OK)
    u16* p2   = p1;                            // p1 dead after rope; sized above

    prep_kernel<<<PREP_QKV_BLOCKS + PREP_RMS_BLOCKS, 256, 0, stream>>>(
        w_qkv, wqkv_bf, x, nscale, h);
    // GEMM1: full-K (z=0 only), 20x8 = 160 gemm blocks + 160 z=1 filler blocks
    // doing the w_out cvt on otherwise-idle CUs
    gemm_bt_8ph<<<dim3(QKVD / 256, TTOK / 256, 2), 512, 163840, stream>>>(
        h, wqkv_bf, p1, QKVD, HIDDEN, HIDDEN, QKVD - 1, QKVD, 1, w_out, wout_bf);
    rope_kernel<<<TTOK, 256, 0, stream>>>(p1, b_qkv, qrot, krot, vrot, 1);
    attn_kernel<<<dim3(TTOK / 16, NKV, 2), 256, 0, stream>>>(qrot, krot, vrot, sinks, attn);
    // GEMM2: split-K z=2 (both z-slices are gemm; no filler), 12x8x2 = 192 blocks
    gemm_bt_8ph<<<dim3((NPAD + 255) / 256, TTOK / 256, 2), 512, 163840, stream>>>(
        attn, wout_bf, p2, NPAD, QD, QD / 2, NPAD - 1, NPAD, 2, nullptr, nullptr);
    reduce2_kernel<<<dim3(3, TTOK), 256, 0, stream>>>(
        p2, p2 + (size_t)TTOK * NPAD, x, b_out, out);
}

// Round 6
// 323.389 us; speedup vs baseline: 1.1007x; 1.0420x over previous
//
#include <hip/hip_runtime.h>
#include <math.h>

typedef unsigned short u16;
typedef unsigned int   u32;
using f32x4  = __attribute__((ext_vector_type(4))) float;
using bf16x8 = __attribute__((ext_vector_type(8))) __bf16;

#define HIDDEN   2880
#define QKVD     5120
#define QD       4096
#define TTOK     2048
#define NKV      8
#define QMULT    8
#define HD       64
#define NPAD     2944   // w_out rows padded to 23*128 (GEMM2 store-guards col<2944)

// prep grid partition (w_out cvt rides in GEMM1's idle CUs)
#define PREP_QKV_BLOCKS  14400   // QKVD*HIDDEN/4/256
#define PREP_RMS_BLOCKS  2048

static __device__ __forceinline__ float bflo(u32 u){ return __uint_as_float(u << 16); }
static __device__ __forceinline__ float bfhi(u32 u){ return __uint_as_float(u & 0xffff0000u); }
static __device__ __forceinline__ u16 f2bf(float f){
    u32 u = __float_as_uint(f);
    u32 r = (u + 0x7fffu + ((u >> 16) & 1u)) >> 16;
    return (u16)r;
}

static __device__ __forceinline__ void glds16(const void* g, void* l) {
    __builtin_amdgcn_global_load_lds(
        (__attribute__((address_space(1))) void*)g,
        (__attribute__((address_space(3))) void*)l,
        16, 0, 0);
}

// Mechanics: raw s_barrier (no waitcnt drain), counted vmcnt, sched_barrier pins.
#define SB0()   __builtin_amdgcn_sched_barrier(0)
#define BARB()  do { SB0(); __builtin_amdgcn_s_barrier(); SB0(); } while (0)
#define LGKM0() do { asm volatile("s_waitcnt lgkmcnt(0)"); SB0(); } while (0)
#define VMW(N)  do { SB0(); asm volatile("s_waitcnt vmcnt(" #N ")"); SB0(); } while (0)

// ---------------- fused prep: w_qkv cvt | rmsnorm ----------------
__global__ __launch_bounds__(256) void prep_kernel(const float* __restrict__ w_qkv,
                                                   u16* __restrict__ wqkv_bf,
                                                   const float* __restrict__ x,
                                                   const float* __restrict__ scale,
                                                   u16* __restrict__ h) {
    const int b = blockIdx.x;
    const int tid = threadIdx.x;
    if (b < PREP_QKV_BLOCKS) {
        int i = b * 256 + tid;
        float4 f = ((const float4*)w_qkv)[i];
        ushort4 o;
        o.x = f2bf(f.x); o.y = f2bf(f.y); o.z = f2bf(f.z); o.w = f2bf(f.w);
        ((ushort4*)wqkv_bf)[i] = o;
    } else {
        const int t = b - PREP_QKV_BLOCKS;
        const float4* xr = (const float4*)(x + (long)t * HIDDEN);
        float4 v[3];
        float ss = 0.f;
        #pragma unroll
        for (int it = 0; it < 3; ++it) {
            int i4 = tid + it * 256;
            if (i4 < 720) {
                v[it] = xr[i4];
                ss += v[it].x*v[it].x + v[it].y*v[it].y + v[it].z*v[it].z + v[it].w*v[it].w;
            }
        }
        #pragma unroll
        for (int off = 32; off > 0; off >>= 1) ss += __shfl_down(ss, off);
        __shared__ float red[4];
        if ((tid & 63) == 0) red[tid >> 6] = ss;
        __syncthreads();
        float tot = red[0] + red[1] + red[2] + red[3];
        float rr = rsqrtf(tot * (1.0f / HIDDEN) + 1e-5f);
        ushort4* hr = (ushort4*)(h + (long)t * HIDDEN);
        #pragma unroll
        for (int it = 0; it < 3; ++it) {
            int i4 = tid + it * 256;
            if (i4 < 720) {
                float4 s4 = ((const float4*)scale)[i4];
                ushort4 o;
                o.x = f2bf(v[it].x * rr * s4.x);
                o.y = f2bf(v[it].y * rr * s4.y);
                o.z = f2bf(v[it].z * rr * s4.z);
                o.w = f2bf(v[it].w * rr * s4.w);
                hr[i4] = o;
            }
        }
    }
}

// -- R6: phase-ahead register-pipelined 256x256/BK=64 GEMM, 2 barriers/K-tile ----
// R5 post-mortem: R2/R5's reads feed the SAME phase's MFMA with lgkmcnt(0) between
// -> all 8 waves' reads drain FIFO-interleaved on the CU-shared LDS pipe, every
// wave's wait releases at ~the same late time, then MFMAs run: per-phase ADDITIVE
// (model 4788 cy/tile == 4827 measured). Fix: reads issued in phase p feed phase
// p+1's MFMA (R3 dataflow) under R5 mechanics (raw barriers, counted vmcnt) ->
// reads(p+1) drain on the LDS pipe UNDER MFMA(p) on the matrix pipe; the
// compiler's auto-inserted counted lgkm waits for the 1-phase-old reads are
// ~satisfied. NO wait between a phase's read-issue and its MFMAs.
// Wave tile 64x128 (wm2=wv>>1: 0..3 M-quad, wn2=wv&1: 0..1 N-half); aq[4][2]
// persists per tile; bq quads ping-pong E/O by phase (all indices compile-time).
// LDS 128 KB: A[2][256][64] + B[2][256][64].
// Schedule (tile t):
//  ph1: read B(t).q1->O        ; stage Bh1(t+1), A(t+2) ; MFMA q0 (E,aq)
//  ph2: read B(t).q2->E        ;                        ; MFMA q1 (O)
//  ph3: read B(t).q3->O        ; MFMA q2 (E) ; VMW(4) ; BARB
//  ph4: read B(t+1).q0->E      ; stage Bh0(t+2) ; MFMA q3 (O) ; read aq<-A(t+1)
//       ; LGKM0 ; BARB
// VMW(4)@end-ph3: outstanding (oldest->newest) = Bh0(t+1)[ph4(t-1)]2,
//  Bh1(t+1)[ph1]2, A(t+2)[ph1]4 -> leaves newest 4, confirms ALL of tile t+1's
//  staged data; barrier propagates cross-wave before ph4 reads slot t+1.
//  Tails: t+2>=NT -> VMW(0); t+1>=NT -> skip.
// LGKM0@end-ph4: net-zero cost (ph1's MFMA q0 needs those 12 reads immediately);
//  guarantees every wave's ph4 reads retired before any wave's ph1 stageA(t+2)
//  overwrites A slot t&1 (cross-wave queue-drain race otherwise).
// Slot safety (2 barriers suffice; skew bounded to one barrier interval):
//  B slot t&1 reads end ph3(t) [quads 1-3] -> stageBh(t+2,0) issues ph4(t) after
//  end-ph3 barrier. A slot t&1 reads end ph4(t-1) [LGKM0'd] -> stageA(t+2)
//  issues ph1(t) after end-ph4 barrier. Bh1(t+1) lands >=VMW'd before ph4 reads.
//  In-window glds-write vs ds_read races: none target the same slot+region.

#define READ_BQ(SET, BASE, NQ) do { \
    SET[0][0] = *(const bf16x8*)((BASE) + (2*(NQ)+0)*2048 + off0); \
    SET[0][1] = *(const bf16x8*)((BASE) + (2*(NQ)+0)*2048 + off1); \
    SET[1][0] = *(const bf16x8*)((BASE) + (2*(NQ)+1)*2048 + off0); \
    SET[1][1] = *(const bf16x8*)((BASE) + (2*(NQ)+1)*2048 + off1); \
} while (0)

#define READ_AQ(BASE) do { \
    _Pragma("unroll") \
    for (int mi_ = 0; mi_ < 4; ++mi_) { \
        aq[mi_][0] = *(const bf16x8*)((BASE) + mi_*2048 + off0); \
        aq[mi_][1] = *(const bf16x8*)((BASE) + mi_*2048 + off1); \
    } \
} while (0)

#define MFMA_N(NQ, SET) do { \
    __builtin_amdgcn_s_setprio(1); \
    _Pragma("unroll") \
    for (int mi_ = 0; mi_ < 4; ++mi_) { \
        _Pragma("unroll") \
        for (int j_ = 0; j_ < 2; ++j_) { \
            acc[mi_][2*(NQ)+j_] = __builtin_amdgcn_mfma_f32_16x16x32_bf16(aq[mi_][0], SET[j_][0], acc[mi_][2*(NQ)+j_], 0, 0, 0); \
            acc[mi_][2*(NQ)+j_] = __builtin_amdgcn_mfma_f32_16x16x32_bf16(aq[mi_][1], SET[j_][1], acc[mi_][2*(NQ)+j_], 0, 0, 0); \
        } \
    } \
    __builtin_amdgcn_s_setprio(0); \
} while (0)

__global__ __launch_bounds__(512, 2) void gemm_bt_8ph(const u16* __restrict__ A,
                                                      const u16* __restrict__ B,
                                                      u16* __restrict__ C0,
                                                      int N, int K, int ksplit,
                                                      int blimit, int colmax,
                                                      int nz_gemm,
                                                      const float* __restrict__ wout_src,
                                                      u16* __restrict__ wout_dst) {
    const int tid  = threadIdx.x;

    if ((int)blockIdx.z >= nz_gemm) {
        // ---- filler blocks: w_out cvt+pad [HIDDEN][QD] f32 -> [NPAD][QD] bf16 ----
        const long nb = (long)gridDim.x * gridDim.y;
        long bidx = (long)blockIdx.y * gridDim.x + blockIdx.x;
        long i = bidx * 512 + tid;
        const long tot = (long)NPAD * QD / 4;
        const long stride = nb * 512;
        for (; i < tot; i += stride) {
            long idx = i * 4;
            int row = (int)(idx >> 12);
            int col = (int)(idx & 4095);
            ushort4 o;
            if (row < HIDDEN) {
                float4 f = *(const float4*)(wout_src + (long)row * QD + col);
                o.x = f2bf(f.x); o.y = f2bf(f.y); o.z = f2bf(f.z); o.w = f2bf(f.w);
            } else {
                o.x = 0; o.y = 0; o.z = 0; o.w = 0;
            }
            ((ushort4*)wout_dst)[i] = o;
        }
        return;
    }

    extern __shared__ u16 smem[];
    u16* const smA = smem;                  // [2][256][64] bf16 (32 KB/slot)
    u16* const smB = smem + 2 * 256 * 64;   // byte 65536, [2][256][64]
    const int lane = tid & 63;
    const int wv   = tid >> 6;              // wave 0..7
    const int wm2  = wv >> 1;               // 0..3 (M quad, 64 rows)
    const int wn2  = wv & 1;                // 0..1 (N half, 128 cols)
    const long m0  = (long)blockIdx.y * 256;
    const long n0  = (long)blockIdx.x * 256;
    const int kbase = blockIdx.z * ksplit;
    int krem = K - kbase; if (krem > ksplit) krem = ksplit;
    const int NT   = krem >> 6;             // K-tiles of 64
    u16* C = C0 + (size_t)blockIdx.z * ((size_t)TTOK * N);

    // staging: per-thread 16B granule; source column pre-swizzled (rule #21 pair)
    const int srow = tid >> 3;                              // 0..63
    const int sg8  = ((tid & 7) ^ (srow & 7)) << 3;         // src elem offset
    // fragment reads: swizzle folds to per-lane constants (row&7 == lane&7)
    const int fr   = lane & 15;
    const int off0 = ((lane >> 4) << 4) ^ ((lane & 7) << 4);
    const int off1 = off0 ^ 64;
    const char* aR = (const char*)smA + (wm2 * 64  + fr) * 128;
    const char* bR = (const char*)smB + (wn2 * 128 + fr) * 128;

    f32x4 acc[4][8];
    #pragma unroll
    for (int i = 0; i < 4; ++i)
        #pragma unroll
        for (int j = 0; j < 8; ++j) acc[i][j] = f32x4{0.f, 0.f, 0.f, 0.f};

    const u16* Asrc = A + (m0 + srow) * (long)K + kbase + sg8;
    auto stageA = [&](int t) {
        char* dst = (char*)smA + (t & 1) * 32768 + wv * 1024;
        const u16* src = Asrc + t * 64;
        #pragma unroll
        for (int hj = 0; hj < 4; ++hj)
            glds16(src + (size_t)(hj * 64) * K, dst + hj * 8192);
    };
    auto stageBh = [&](int t, int h) {
        char* dst = (char*)smB + (t & 1) * 32768 + (h * 128 + wv * 8) * 128;
        #pragma unroll
        for (int j = 0; j < 2; ++j) {
            long r = n0 + h * 128 + j * 64 + srow;
            if (r > blimit) r = blimit;   // clamp into zero-padded rows
            glds16(B + (size_t)r * K + kbase + t * 64 + sg8, dst + j * 8192);
        }
    };

    bf16x8 aq[4][2], bqE[2][2], bqO[2][2];

    // prologue (mirrors steady state): issue A(0),B(0) then A(1),Bh0(1).
    // VMW(6) leaves the newest 6 (A(1)+Bh0(1)) -> A(0),B(0) landed.
    stageA(0);
    stageBh(0, 0); stageBh(0, 1);
    if (NT > 1) {
        stageA(1);
        stageBh(1, 0);
        VMW(6);
    } else {
        VMW(0);
    }
    BARB();
    READ_BQ(bqE, bR, 0);      // B(0).q0
    READ_AQ(aR);              // A(0)
    LGKM0();                  // all waves' reads retired before ph1 stages A(2)
    BARB();

    for (int t = 0; t < NT; ++t) {
        const char* aS1 = aR + ((t + 1) & 1) * 32768;   // A slot t+1
        const char* bS  = bR + (t & 1) * 32768;         // B slot t
        const char* bS1 = bR + ((t + 1) & 1) * 32768;   // B slot t+1
        // ---- ph1: read q1->O; stage Bh1(t+1) THEN A(t+2); MFMA q0 (no wait
        //      between read-issue and MFMA: q0 frags were read last phase)
        READ_BQ(bqO, bS, 1);
        if (t + 1 < NT) stageBh(t + 1, 1);
        if (t + 2 < NT) stageA(t + 2);
        MFMA_N(0, bqE);
        SB0();
        // ---- ph2: read q2->E; MFMA q1
        READ_BQ(bqE, bS, 2);
        MFMA_N(1, bqO);
        SB0();
        // ---- ph3: read q3->O; MFMA q2; counted checkpoint + barrier (confirms
        //      tile t+1 staged data; protects B slot t&1 for ph4's stage)
        READ_BQ(bqO, bS, 3);
        MFMA_N(2, bqE);
        if (t + 2 < NT)      VMW(4);
        else if (t + 1 < NT) VMW(0);
        BARB();
        // ---- ph4: read B(t+1).q0->E; stage Bh0(t+2); MFMA q3; read aq(t+1);
        //      LGKM0 (net-zero: ph1's MFMA needs these reads) + barrier
        if (t + 1 < NT) READ_BQ(bqE, bS1, 0);
        if (t + 2 < NT) stageBh(t + 2, 0);
        MFMA_N(3, bqO);
        if (t + 1 < NT) READ_AQ(aS1);
        LGKM0();
        BARB();
    }

    // epilogue: C/D layout col=lane&15, row=(lane>>4)*4+reg  [m89-verified]
    const int cr = (lane >> 4) * 4;
    const int cc = lane & 15;
    #pragma unroll
    for (int nf = 0; nf < 8; ++nf) {
        long col = n0 + wn2 * 128 + nf * 16 + cc;
        if (col < colmax) {
            #pragma unroll
            for (int mi = 0; mi < 4; ++mi) {
                long row = m0 + wm2 * 64 + mi * 16 + cr;
                #pragma unroll
                for (int r2 = 0; r2 < 4; ++r2)
                    C[(row + r2) * (long)N + col] = f2bf(acc[mi][nf][r2]);
            }
        }
    }
}

// ------- RoPE (YaRN), consumes nsplit GEMM1 split-K partials + bias -------------
__global__ __launch_bounds__(256) void rope_kernel(const u16* __restrict__ p1,
                                                   const float* __restrict__ b_qkv,
                                                   u16* __restrict__ qr,
                                                   u16* __restrict__ kr,
                                                   u16* __restrict__ vr,
                                                   int nsplit) {
    const int t = blockIdx.x;
    const int tid = threadIdx.x;
    __shared__ float cs[32], sn[32];
    if (tid < 32) {
        float fi = (float)tid;
        float freq   = exp2f(17.1946032f * (fi * (1.0f / 32.0f)));   // 150000^(i/32)
        float interp = 1.0f / (32.0f * freq);
        float extra  = 1.0f / freq;
        float ramp   = (fi - 8.0927802f) * (1.0f / (17.3980220f - 8.0927802f));
        float rc     = fminf(fmaxf(ramp, 0.0f), 1.0f);               // = 1 - mask
        float invf   = interp * rc + extra * (1.0f - rc);
        float ang    = (float)t * invf;
        cs[tid] = cosf(ang) * 1.3465736f;                            // * concentration
        sn[tid] = sinf(ang) * 1.3465736f;
    }
    __syncthreads();
    const u16* rowA = p1 + (long)t * QKVD;
    auto pair = [&](int col) -> float2 {
        float2 bb = *(const float2*)(b_qkv + col);
        float a = bb.x, b = bb.y;
        for (int s = 0; s < nsplit; ++s) {
            u32 u = *(const u32*)(rowA + (size_t)s * TTOK * QKVD + col);
            a += bflo(u); b += bfhi(u);
        }
        return make_float2(a, b);
    };
    // Q: 64 heads x 32 pairs
    for (int p = tid; p < 2048; p += 256) {
        int hd2 = p >> 5, i = p & 31;
        float2 ab = pair(hd2 * 64 + 2 * i);
        float o1 = ab.x * cs[i] - ab.y * sn[i];
        float o2 = ab.y * cs[i] + ab.x * sn[i];
        *(u32*)(qr + (long)t * QD + hd2 * 64 + 2 * i) = (u32)f2bf(o1) | ((u32)f2bf(o2) << 16);
    }
    // K: 8 heads x 32 pairs == 256 threads; head-major layout [kv][t][64]
    {
        int kv = tid >> 5, i = tid & 31;
        float2 ab = pair(QD + kv * 64 + 2 * i);
        float o1 = ab.x * cs[i] - ab.y * sn[i];
        float o2 = ab.y * cs[i] + ab.x * sn[i];
        *(u32*)(kr + ((long)kv * TTOK + t) * HD + 2 * i) = (u32)f2bf(o1) | ((u32)f2bf(o2) << 16);
    }
    // V: 8 heads x 64 = 256 u32; head-major [kv][t][64]
    {
        int kv = tid >> 5, d2 = tid & 31;
        float2 ab = pair(QD + 512 + kv * 64 + 2 * d2);
        *(u32*)(vr + ((long)kv * TTOK + t) * HD + 2 * d2) = (u32)f2bf(ab.x) | ((u32)f2bf(ab.y) << 16);
    }
}

// ---------------- MFMA sliding-window attention with sink ----------------
__global__ __launch_bounds__(256, 2) void attn_kernel(const u16* __restrict__ qr,
                                                      const u16* __restrict__ kr,
                                                      const u16* __restrict__ vr,
                                                      const float* __restrict__ sinks,
                                                      u16* __restrict__ o) {
    const int t0  = blockIdx.x * 16;
    const int h   = blockIdx.y;
    const int qhg = blockIdx.z;
    const int tid = threadIdx.x;
    const int lane = tid & 63, wv = tid >> 6;
    __shared__ __align__(16) u16 ks[144][72];    // K rows [key][64+pad]
    __shared__ __align__(16) u16 Vt[64][168];    // V^T [d][key], cols 144..159 zero
    __shared__ __align__(16) u16 P [4][16][168]; // per-wave P [token][key], cols 144..159 zero
    const u16* kb = kr + (long)h * TTOK * HD;
    const u16* vb = vr + (long)h * TTOK * HD;

    // stage K rows (coalesced)
    #pragma unroll
    for (int i = 0; i < 5; ++i) {
        int idx = i * 256 + tid;
        if (idx < 144 * 8) {
            int rr = idx >> 3, c = idx & 7;
            int tk = t0 - 128 + rr;
            int tks = tk < 0 ? 0 : tk;          // clamped; masked later
            *(uint4*)&ks[rr][c * 8] = *(const uint4*)(kb + (long)tks * HD + c * 8);
        }
    }
    // stage V transposed: thread -> one key, 8 dims per pass
    #pragma unroll
    for (int c4 = 0; c4 < 8; ++c4) {
        if (tid < 144) {
            int tk = t0 - 128 + tid;
            int tks = tk < 0 ? 0 : tk;
            uint4 v4 = *(const uint4*)(vb + (long)tks * HD + c4 * 8);
            int d0 = c4 * 8;
            Vt[d0+0][tid] = (u16)(v4.x & 0xffff); Vt[d0+1][tid] = (u16)(v4.x >> 16);
            Vt[d0+2][tid] = (u16)(v4.y & 0xffff); Vt[d0+3][tid] = (u16)(v4.y >> 16);
            Vt[d0+4][tid] = (u16)(v4.z & 0xffff); Vt[d0+5][tid] = (u16)(v4.z >> 16);
            Vt[d0+6][tid] = (u16)(v4.w & 0xffff); Vt[d0+7][tid] = (u16)(v4.w >> 16);
        }
    }
    if (tid < 128) {
        *(uint4*)&Vt[tid >> 1][144 + (tid & 1) * 8] = uint4{0, 0, 0, 0};
    }
    if (lane < 32) {
        *(uint4*)&P[wv][lane >> 1][144 + (lane & 1) * 8] = uint4{0, 0, 0, 0};
    }
    __syncthreads();

    const int qh   = qhg * 4 + wv;
    const int head = h * QMULT + qh;
    const int fr = lane & 15, fk = (lane >> 4) * 8;
    const int cr = (lane >> 4) * 4;

    const u16* qrow = qr + (long)(t0 + fr) * QD + head * HD;
    bf16x8 qf0 = *(const bf16x8*)(qrow + fk);
    bf16x8 qf1 = *(const bf16x8*)(qrow + 32 + fk);

    const int kmin = 128 - t0;          // kk >= kmin <=> key token >= 0
    float lsum[4] = {0.f, 0.f, 0.f, 0.f};

    for (int nt = 0; nt < 9; ++nt) {
        bf16x8 b0 = *(const bf16x8*)&ks[nt * 16 + fr][fk];
        bf16x8 b1 = *(const bf16x8*)&ks[nt * 16 + fr][32 + fk];
        f32x4 s = f32x4{0.f, 0.f, 0.f, 0.f};
        s = __builtin_amdgcn_mfma_f32_16x16x32_bf16(qf0, b0, s, 0, 0, 0);
        s = __builtin_amdgcn_mfma_f32_16x16x32_bf16(qf1, b1, s, 0, 0, 0);
        const int kk = nt * 16 + fr;    // C-layout col = lane&15
        #pragma unroll
        for (int r = 0; r < 4; ++r) {
            int row = cr + r;           // token index within tile
            bool valid = (kk >= row) && (kk <= row + 128) && (kk >= kmin);
            float p = valid ? __expf(s[r] * 0.125f) : 0.0f;
            lsum[r] += p;
            P[wv][row][kk] = f2bf(p);
        }
    }

    f32x4 oacc[4];
    #pragma unroll
    for (int dt = 0; dt < 4; ++dt) oacc[dt] = f32x4{0.f, 0.f, 0.f, 0.f};
    #pragma unroll
    for (int k5 = 0; k5 < 5; ++k5) {
        const int k0 = k5 * 32;
        bf16x8 pa = *(const bf16x8*)&P[wv][fr][k0 + fk];
        #pragma unroll
        for (int dt = 0; dt < 4; ++dt) {
            bf16x8 vf = *(const bf16x8*)&Vt[dt * 16 + fr][k0 + fk];
            oacc[dt] = __builtin_amdgcn_mfma_f32_16x16x32_bf16(pa, vf, oacc[dt], 0, 0, 0);
        }
    }

    #pragma unroll
    for (int r = 0; r < 4; ++r) {
        float v = lsum[r];
        v += __shfl_xor(v, 1);
        v += __shfl_xor(v, 2);
        v += __shfl_xor(v, 4);
        v += __shfl_xor(v, 8);
        lsum[r] = v;
    }
    const float sk = exp2f(sinks[head]);
    float inv[4];
    #pragma unroll
    for (int r = 0; r < 4; ++r) inv[r] = 1.0f / (lsum[r] + sk);

    #pragma unroll
    for (int dt = 0; dt < 4; ++dt) {
        #pragma unroll
        for (int r = 0; r < 4; ++r) {
            o[(long)(t0 + cr + r) * QD + head * HD + dt * 16 + fr] = f2bf(oacc[dt][r] * inv[r]);
        }
    }
}

// ---------------- reduce GEMM2 partials + bias + residual -> out ----------------
__global__ __launch_bounds__(256) void reduce2_kernel(const u16* __restrict__ p2a,
                                                      const u16* __restrict__ p2b,
                                                      const float* __restrict__ x,
                                                      const float* __restrict__ b_out,
                                                      float* __restrict__ out) {
    const int row = blockIdx.y;
    const int c4 = blockIdx.x * 256 + threadIdx.x;   // float4 index within row
    if (c4 >= 720) return;
    const int col = c4 * 4;
    ushort4 ua = *(const ushort4*)(p2a + (long)row * NPAD + col);
    ushort4 ub = *(const ushort4*)(p2b + (long)row * NPAD + col);
    float4 xv = *(const float4*)(x + (long)row * HIDDEN + col);
    float4 bv = *(const float4*)(b_out + col);
    float4 o;
    o.x = xv.x + bv.x + __uint_as_float((u32)ua.x << 16) + __uint_as_float((u32)ub.x << 16);
    o.y = xv.y + bv.y + __uint_as_float((u32)ua.y << 16) + __uint_as_float((u32)ub.y << 16);
    o.z = xv.z + bv.z + __uint_as_float((u32)ua.z << 16) + __uint_as_float((u32)ub.z << 16);
    o.w = xv.w + bv.w + __uint_as_float((u32)ua.w << 16) + __uint_as_float((u32)ub.w << 16);
    *(float4*)(out + (long)row * HIDDEN + col) = o;
}

// ---------------- launcher ----------------
extern "C" void kernel_launch(void* const* d_in, const int* in_sizes, int n_in,
                              void* d_out, int out_size, void* d_ws, size_t ws_size,
                              hipStream_t stream) {
    const float* x      = (const float*)d_in[0];
    const float* nscale = (const float*)d_in[1];
    const float* w_qkv  = (const float*)d_in[2];
    const float* b_qkv  = (const float*)d_in[3];
    const float* sinks  = (const float*)d_in[4];
    const float* w_out  = (const float*)d_in[5];
    const float* b_out  = (const float*)d_in[6];
    float* out = (float*)d_out;

    static int smem_set = 0;
    if (!smem_set) {
        hipFuncSetAttribute((const void*)gemm_bt_8ph,
                            hipFuncAttributeMaxDynamicSharedMemorySize, 131072);
        smem_set = 1;
    }

    char* ws = (char*)d_ws;
    size_t off = 0;
    auto alloc = [&](size_t bytes) { void* p = ws + off; off += (bytes + 255) & ~(size_t)255; return p; };
    const size_t p1_bytes  = (size_t)TTOK * QKVD * 2;          // 21.0 MB (GEMM1 out)
    const size_t p2_bytes  = (size_t)2 * TTOK * NPAD * 2;      // 24.1 MB (GEMM2 partials)
    u16* wqkv_bf = (u16*)alloc((size_t)QKVD * HIDDEN * 2);     // 29.5 MB
    u16* wout_bf = (u16*)alloc((size_t)NPAD * QD * 2);         // 24.1 MB
    u16* h       = (u16*)alloc((size_t)TTOK * HIDDEN * 2);     // 11.8 MB
    u16* p1      = (u16*)alloc(p1_bytes > p2_bytes ? p1_bytes : p2_bytes);
    u16* qrot    = (u16*)alloc((size_t)TTOK * QD * 2);         // 16.8 MB
    // aliases (dead-after analysis):
    u16* attn = wqkv_bf;                       // wqkv_bf dead after gemm1 (16.8 MB)
    u16* krot = wqkv_bf + (size_t)TTOK * QD;   // wqkv tail: +2.1 MB
    u16* vrot = krot + (size_t)NKV * TTOK * HD;// +2.1 MB (total 21.0 <= 29.5 OK)
    u16* p2   = p1;                            // p1 dead after rope; sized above

    prep_kernel<<<PREP_QKV_BLOCKS + PREP_RMS_BLOCKS, 256, 0, stream>>>(
        w_qkv, wqkv_bf, x, nscale, h);
    // GEMM1: full-K (z=0 only), 20x8 = 160 gemm blocks + 160 z=1 filler blocks
    // doing the w_out cvt on otherwise-idle CUs
    gemm_bt_8ph<<<dim3(QKVD / 256, TTOK / 256, 2), 512, 131072, stream>>>(
        h, wqkv_bf, p1, QKVD, HIDDEN, HIDDEN, QKVD - 1, QKVD, 1, w_out, wout_bf);
    rope_kernel<<<TTOK, 256, 0, stream>>>(p1, b_qkv, qrot, krot, vrot, 1);
    attn_kernel<<<dim3(TTOK / 16, NKV, 2), 256, 0, stream>>>(qrot, krot, vrot, sinks, attn);
    // GEMM2: split-K z=2 (both z-slices are gemm; no filler), 12x8x2 = 192 blocks
    gemm_bt_8ph<<<dim3((NPAD + 255) / 256, TTOK / 256, 2), 512, 131072, stream>>>(
        attn, wout_bf, p2, NPAD, QD, QD / 2, NPAD - 1, NPAD, 2, nullptr, nullptr);
    reduce2_kernel<<<dim3(3, TTOK), 256, 0, stream>>>(
        p2, p2 + (size_t)TTOK * NPAD, x, b_out, out);
}